// Round 12
// baseline (2045.742 us; speedup 1.0000x reference)
//
#include <hip/hip_runtime.h>

typedef __attribute__((ext_vector_type(4))) float f32x4;
typedef _Float16 f16;
typedef __attribute__((ext_vector_type(2))) _Float16 f16x2;
typedef __attribute__((ext_vector_type(8))) _Float16 f16x8;

#define T_LEN 2048
#define FEATN 128
#define H 50
#define H3 150
#define XW_STRIDE 160

#define RPB 16          // rows per block (phase 2)
#define THR2 512        // 8 waves
#define HT_STRIDE 72    // f16 units, 144B rows (16B aligned)
#define CT_STRIDE 17    // f32 units, bank-spread
#define STG_F16 (RPB * XW_STRIDE)  // 2560 f16 = 5120B per stage buffer
#define NSTG 5

__device__ __forceinline__ float rcpf(float x) { return __builtin_amdgcn_rcpf(x); }

// ---------------- Phase 1: xw[m][k] = x[m][:] @ W[:][k]  (f16 out, no bias) ----
__global__ __launch_bounds__(256) void xw_gemm(const float* __restrict__ x,
                                               const float* __restrict__ W,
                                               f16* __restrict__ xw) {
  __shared__ f16 Wt[160 * 136];  // [n][k], row stride 136 halves
  const int tid = threadIdx.x;
  for (int idx = tid; idx < FEATN * H3; idx += 256) {
    int f = idx / H3;
    int n = idx - f * H3;
    Wt[n * 136 + f] = (f16)W[idx];
  }
  for (int idx = tid; idx < 10 * FEATN; idx += 256) {  // zero-pad n = 150..159
    int n = H3 + (idx >> 7);
    int f = idx & 127;
    Wt[n * 136 + f] = (f16)0.f;
  }
  __syncthreads();

  const int wid = tid >> 6;
  const int lane = tid & 63;
  const int l15 = lane & 15;
  const int g = lane >> 4;
  const long row0 = (long)blockIdx.x * 128 + wid * 32;

  f16x8 a[2][4];
#pragma unroll
  for (int sub = 0; sub < 2; ++sub) {
    const float* xp = x + (row0 + sub * 16 + l15) * FEATN + g * 8;
#pragma unroll
    for (int kk = 0; kk < 4; ++kk) {
      f32x4 p0 = *(const f32x4*)(xp + kk * 32);
      f32x4 p1 = *(const f32x4*)(xp + kk * 32 + 4);
      f16x8 v;
      v[0] = (f16)p0[0]; v[1] = (f16)p0[1]; v[2] = (f16)p0[2]; v[3] = (f16)p0[3];
      v[4] = (f16)p1[0]; v[5] = (f16)p1[1]; v[6] = (f16)p1[2]; v[7] = (f16)p1[3];
      a[sub][kk] = v;
    }
  }

  for (int nt = 0; nt < 10; ++nt) {
    const f16* bp = &Wt[(nt * 16 + l15) * 136 + g * 8];
    f16x8 bf0 = *(const f16x8*)(bp);
    f16x8 bf1 = *(const f16x8*)(bp + 32);
    f16x8 bf2 = *(const f16x8*)(bp + 64);
    f16x8 bf3 = *(const f16x8*)(bp + 96);
    f32x4 acc0 = {0.f, 0.f, 0.f, 0.f};
    f32x4 acc1 = {0.f, 0.f, 0.f, 0.f};
    acc0 = __builtin_amdgcn_mfma_f32_16x16x32_f16(a[0][0], bf0, acc0, 0, 0, 0);
    acc0 = __builtin_amdgcn_mfma_f32_16x16x32_f16(a[0][1], bf1, acc0, 0, 0, 0);
    acc0 = __builtin_amdgcn_mfma_f32_16x16x32_f16(a[0][2], bf2, acc0, 0, 0, 0);
    acc0 = __builtin_amdgcn_mfma_f32_16x16x32_f16(a[0][3], bf3, acc0, 0, 0, 0);
    acc1 = __builtin_amdgcn_mfma_f32_16x16x32_f16(a[1][0], bf0, acc1, 0, 0, 0);
    acc1 = __builtin_amdgcn_mfma_f32_16x16x32_f16(a[1][1], bf1, acc1, 0, 0, 0);
    acc1 = __builtin_amdgcn_mfma_f32_16x16x32_f16(a[1][2], bf2, acc1, 0, 0, 0);
    acc1 = __builtin_amdgcn_mfma_f32_16x16x32_f16(a[1][3], bf3, acc1, 0, 0, 0);
    int col = nt * 16 + l15;
    if (col < H3) {
#pragma unroll
      for (int r = 0; r < 4; ++r) {
        long rowA = row0 + g * 4 + r;
        xw[rowA * XW_STRIDE + col] = (f16)acc0[r];
        xw[(rowA + 16) * XW_STRIDE + col] = (f16)acc1[r];
      }
    }
  }
}

// ---------------- Phase 2: MFMA GRU — 16 rows/block, 8 waves -----------------
// Per step: h[16][64]@U[64][160] via MFMA (U = loop-invariant B-frags), C
// stored transposed in LDS, gate phase (wave w -> rows {w, w+8}, lane k<50),
// h written back as f16 A-tile. Raw s_barrier + counted lgkm/vmcnt waits keep
// the global_load_lds xw pipeline (distance 4, 5 buffers) in flight.
__global__ __launch_bounds__(512, 1) void gru_mfma(const f16* __restrict__ xw,
                                                   const float* __restrict__ U,
                                                   const float* __restrict__ bias,
                                                   const float* __restrict__ W2,
                                                   const float* __restrict__ b2,
                                                   float* __restrict__ out) {
  __shared__ __align__(16) f16 hT[RPB * HT_STRIDE];
  __shared__ __align__(16) float CT[160 * CT_STRIDE];
  __shared__ __align__(16) f16 stage[NSTG * STG_F16];

  const int tid = threadIdx.x;
  const int blk = blockIdx.x;
  const int lane = tid & 63;
  const int wv = tid >> 6;  // 0..7

  for (int i = tid; i < RPB * HT_STRIDE; i += THR2) hT[i] = (f16)0.f;

  // B-fragments: waves 0,1 own 2 N-tiles; waves 2..7 own 1. (10 tiles = 160 cols)
  const int ntile = (wv < 2) ? 2 : 1;
  const int tile0 = (wv < 2) ? (2 * wv) : (wv + 2);
  const int bcol = lane & 15;
  const int bk0 = (lane >> 4) * 8;
  f16x8 bf[2][2];
#pragma unroll
  for (int i = 0; i < 2; ++i) {
    int nt = tile0 + i;
#pragma unroll
    for (int kh = 0; kh < 2; ++kh) {
      f16x8 v;
#pragma unroll
      for (int j = 0; j < 8; ++j) {
        int k = kh * 32 + bk0 + j;
        int col = nt * 16 + bcol;
        float uv = (i < ntile && k < H && col < H3) ? U[k * H3 + col] : 0.f;
        v[j] = (f16)uv;
      }
      bf[i][kh] = v;
    }
  }

  // Gate-phase constants: lane = hidden index k, wave -> rows {wv, wv+8}
  const int gk = lane;
  const bool gact = gk < H;
  const int gkc = gact ? gk : 0;
  const float bzc = bias[gkc] + bias[H3 + gkc];
  const float brc = bias[H + gkc] + bias[H3 + H + gkc];
  const float b0h = bias[2 * H + gkc];
  const float b1h = bias[H3 + 2 * H + gkc];
  const int r0 = wv, r1 = wv + 8;
  float h0 = 0.f, h1 = 0.f;

  // xw staging: 5 chunks of 1024B per step ([16][320B] flat), waves 0..4 issue.
  const bool issuer = (wv < NSTG);
  const char* srcp = nullptr;
  if (issuer) {
    int p = wv * 1024 + lane * 16;            // byte pos in [16][320] flat tile
    int prow = p / 320;
    int pcolb = p - prow * 320;
    srcp = (const char*)xw + ((size_t)(blk * RPB + prow) * T_LEN) * 320 + pcolb;
  }

  __syncthreads();  // hT zeros visible (pre-pipeline; drain harmless here)

  // Prologue: stage buffers 0..3 (steps 0..3)
  if (issuer) {
#pragma unroll
    for (int i = 0; i < 4; ++i) {
      __builtin_amdgcn_global_load_lds(srcp, stage + i * STG_F16 + wv * 512, 16, 0, 0);
      srcp += 320;
    }
  }

  const int arow = lane & 15;
  const int ag = lane >> 4;
  const f16* aptr = hT + arow * HT_STRIDE + ag * 8;

  int rb = 0;                 // read buffer offset (f16 units)
  int wb = 4 * STG_F16;       // write buffer offset

  for (int t = 0; t < T_LEN; ++t) {
    // issue stage for t+4 (dummy re-issues near the end keep vmcnt uniform)
    if (issuer) {
      __builtin_amdgcn_global_load_lds(srcp, stage + wb + wv * 512, 16, 0, 0);
      if (t < T_LEN - 5) srcp += 320;
    }

    // A-fragments of h
    f16x8 a0 = *(const f16x8*)(aptr);
    f16x8 a1 = *(const f16x8*)(aptr + 32);

    // MFMA + transposed C store
    {
      f32x4 acc = {0.f, 0.f, 0.f, 0.f};
      acc = __builtin_amdgcn_mfma_f32_16x16x32_f16(a0, bf[0][0], acc, 0, 0, 0);
      acc = __builtin_amdgcn_mfma_f32_16x16x32_f16(a1, bf[0][1], acc, 0, 0, 0);
      float* cp = CT + (tile0 * 16 + bcol) * CT_STRIDE + ag * 4;
      cp[0] = acc[0]; cp[1] = acc[1]; cp[2] = acc[2]; cp[3] = acc[3];
    }
    if (ntile == 2) {
      f32x4 acc = {0.f, 0.f, 0.f, 0.f};
      acc = __builtin_amdgcn_mfma_f32_16x16x32_f16(a0, bf[1][0], acc, 0, 0, 0);
      acc = __builtin_amdgcn_mfma_f32_16x16x32_f16(a1, bf[1][1], acc, 0, 0, 0);
      float* cp = CT + ((tile0 + 1) * 16 + bcol) * CT_STRIDE + ag * 4;
      cp[0] = acc[0]; cp[1] = acc[1]; cp[2] = acc[2]; cp[3] = acc[3];
    }

    // barrier 1: C stores + my stage(t-4) loads done -> gates may read
    __builtin_amdgcn_sched_barrier(0);
    asm volatile("s_waitcnt lgkmcnt(0)");
    if (issuer) asm volatile("s_waitcnt vmcnt(15)");
    __builtin_amdgcn_sched_barrier(0);
    __builtin_amdgcn_s_barrier();

    // gate phase
    if (gact) {
      {
        float iz = CT[gk * CT_STRIDE + r0];
        float ir = CT[(gk + H) * CT_STRIDE + r0];
        float ih = CT[(gk + 2 * H) * CT_STRIDE + r0];
        float xz = (float)stage[rb + r0 * XW_STRIDE + gk];
        float xr = (float)stage[rb + r0 * XW_STRIDE + H + gk];
        float xh = (float)stage[rb + r0 * XW_STRIDE + 2 * H + gk];
        float az = iz + bzc + xz;
        float ar = ir + brc + xr;
        float zz = rcpf(1.f + __expf(-az));
        float rr = rcpf(1.f + __expf(-ar));
        float ah = fmaf(rr, ih + b1h, xh + b0h);
        float th = fmaf(2.f, rcpf(1.f + __expf(-2.f * ah)), -1.f);
        h0 = fmaf(zz, h0 - th, th);
        hT[r0 * HT_STRIDE + gk] = (f16)h0;
      }
      {
        float iz = CT[gk * CT_STRIDE + r1];
        float ir = CT[(gk + H) * CT_STRIDE + r1];
        float ih = CT[(gk + 2 * H) * CT_STRIDE + r1];
        float xz = (float)stage[rb + r1 * XW_STRIDE + gk];
        float xr = (float)stage[rb + r1 * XW_STRIDE + H + gk];
        float xh = (float)stage[rb + r1 * XW_STRIDE + 2 * H + gk];
        float az = iz + bzc + xz;
        float ar = ir + brc + xr;
        float zz = rcpf(1.f + __expf(-az));
        float rr = rcpf(1.f + __expf(-ar));
        float ah = fmaf(rr, ih + b1h, xh + b0h);
        float th = fmaf(2.f, rcpf(1.f + __expf(-2.f * ah)), -1.f);
        h1 = fmaf(zz, h1 - th, th);
        hT[r1 * HT_STRIDE + gk] = (f16)h1;
      }
    }

    // barrier 2: h writes done -> next step's A-reads safe
    __builtin_amdgcn_sched_barrier(0);
    asm volatile("s_waitcnt lgkmcnt(0)");
    __builtin_amdgcn_sched_barrier(0);
    __builtin_amdgcn_s_barrier();

    rb += STG_F16; if (rb == NSTG * STG_F16) rb = 0;
    wb += STG_F16; if (wb == NSTG * STG_F16) wb = 0;
  }

  // Epilogue: LeakyReLU -> dense(50->8) -> softmax. (Loop done; __syncthreads ok.)
  __syncthreads();
  if (gact) {
    CT[r0 * 64 + gk] = h0 >= 0.f ? h0 : 0.3f * h0;
    CT[r1 * 64 + gk] = h1 >= 0.f ? h1 : 0.3f * h1;
  }
  __syncthreads();
  if (tid < 128) {
    int row = tid >> 3, o = tid & 7;
    float acc = b2[o];
#pragma unroll
    for (int j = 0; j < H; ++j) acc = fmaf(CT[row * 64 + j], W2[j * 8 + o], acc);
    CT[1024 + row * 8 + o] = acc;
  }
  __syncthreads();
  if (tid < 128) {
    int row = tid >> 3, o = tid & 7;
    float m = CT[1024 + row * 8];
#pragma unroll
    for (int i = 1; i < 8; ++i) m = fmaxf(m, CT[1024 + row * 8 + i]);
    float s = 0.f;
#pragma unroll
    for (int i = 0; i < 8; ++i) s += __expf(CT[1024 + row * 8 + i] - m);
    out[(blk * RPB + row) * 8 + o] = __expf(CT[1024 + row * 8 + o] - m) / s;
  }
}

extern "C" void kernel_launch(void* const* d_in, const int* in_sizes, int n_in,
                              void* d_out, int out_size, void* d_ws, size_t ws_size,
                              hipStream_t stream) {
  const float* x = (const float*)d_in[0];
  const float* W = (const float*)d_in[1];
  const float* U = (const float*)d_in[2];
  const float* bias = (const float*)d_in[3];
  const float* W2 = (const float*)d_in[4];
  const float* b2 = (const float*)d_in[5];
  float* out = (float*)d_out;
  f16* xw = (f16*)d_ws;  // [B*T][160] f16, ~168 MB

  xw_gemm<<<4096, 256, 0, stream>>>(x, W, xw);
  gru_mfma<<<16, 512, 0, stream>>>(xw, U, bias, W2, b2, out);
}

// Round 15
// 616.144 us; speedup vs baseline: 3.3202x; 3.3202x over previous
//
#include <hip/hip_runtime.h>

typedef __attribute__((ext_vector_type(4))) float f32x4;
typedef _Float16 f16;
typedef __attribute__((ext_vector_type(2))) _Float16 f16x2;
typedef __attribute__((ext_vector_type(8))) _Float16 f16x8;

#define T_LEN 2048
#define B_SZ 256
#define FEATN 128
#define H 50
#define H3 150
#define XW_STRIDE 160

#define UROW 168  // f16 units per lane row = 336B; conflict-free b128 stride

__device__ __forceinline__ float rcpf(float x) { return __builtin_amdgcn_rcpf(x); }

// Proven-numerics dot (rounds 3-12, absmax 0.00195): builtin if present.
__device__ __forceinline__ float dot2f(f16x2 a, f16x2 b, float c) {
#if __has_builtin(__builtin_amdgcn_fdot2)
  return __builtin_amdgcn_fdot2(a, b, c, false);
#else
  return fmaf((float)a[1], (float)b[1], fmaf((float)a[0], (float)b[0], c));
#endif
}

// ---------------- Phase 1: xw[m][k] = x[m][:] @ W[:][k]  (f16 out, no bias) ----
__global__ __launch_bounds__(256) void xw_gemm(const float* __restrict__ x,
                                               const float* __restrict__ W,
                                               f16* __restrict__ xw) {
  __shared__ f16 Wt[160 * 136];  // [n][k], row stride 136 halves
  const int tid = threadIdx.x;
  for (int idx = tid; idx < FEATN * H3; idx += 256) {
    int f = idx / H3;
    int n = idx - f * H3;
    Wt[n * 136 + f] = (f16)W[idx];
  }
  for (int idx = tid; idx < 10 * FEATN; idx += 256) {  // zero-pad n = 150..159
    int n = H3 + (idx >> 7);
    int f = idx & 127;
    Wt[n * 136 + f] = (f16)0.f;
  }
  __syncthreads();

  const int wid = tid >> 6;
  const int lane = tid & 63;
  const int l15 = lane & 15;
  const int g = lane >> 4;
  const long row0 = (long)blockIdx.x * 128 + wid * 32;

  f16x8 a[2][4];
#pragma unroll
  for (int sub = 0; sub < 2; ++sub) {
    const float* xp = x + (row0 + sub * 16 + l15) * FEATN + g * 8;
#pragma unroll
    for (int kk = 0; kk < 4; ++kk) {
      f32x4 p0 = *(const f32x4*)(xp + kk * 32);
      f32x4 p1 = *(const f32x4*)(xp + kk * 32 + 4);
      f16x8 v;
      v[0] = (f16)p0[0]; v[1] = (f16)p0[1]; v[2] = (f16)p0[2]; v[3] = (f16)p0[3];
      v[4] = (f16)p1[0]; v[5] = (f16)p1[1]; v[6] = (f16)p1[2]; v[7] = (f16)p1[3];
      a[sub][kk] = v;
    }
  }

  for (int nt = 0; nt < 10; ++nt) {
    const f16* bp = &Wt[(nt * 16 + l15) * 136 + g * 8];
    f16x8 bf0 = *(const f16x8*)(bp);
    f16x8 bf1 = *(const f16x8*)(bp + 32);
    f16x8 bf2 = *(const f16x8*)(bp + 64);
    f16x8 bf3 = *(const f16x8*)(bp + 96);
    f32x4 acc0 = {0.f, 0.f, 0.f, 0.f};
    f32x4 acc1 = {0.f, 0.f, 0.f, 0.f};
    acc0 = __builtin_amdgcn_mfma_f32_16x16x32_f16(a[0][0], bf0, acc0, 0, 0, 0);
    acc0 = __builtin_amdgcn_mfma_f32_16x16x32_f16(a[0][1], bf1, acc0, 0, 0, 0);
    acc0 = __builtin_amdgcn_mfma_f32_16x16x32_f16(a[0][2], bf2, acc0, 0, 0, 0);
    acc0 = __builtin_amdgcn_mfma_f32_16x16x32_f16(a[0][3], bf3, acc0, 0, 0, 0);
    acc1 = __builtin_amdgcn_mfma_f32_16x16x32_f16(a[1][0], bf0, acc1, 0, 0, 0);
    acc1 = __builtin_amdgcn_mfma_f32_16x16x32_f16(a[1][1], bf1, acc1, 0, 0, 0);
    acc1 = __builtin_amdgcn_mfma_f32_16x16x32_f16(a[1][2], bf2, acc1, 0, 0, 0);
    acc1 = __builtin_amdgcn_mfma_f32_16x16x32_f16(a[1][3], bf3, acc1, 0, 0, 0);
    int col = nt * 16 + l15;
    if (col < H3) {
#pragma unroll
      for (int r = 0; r < 4; ++r) {
        long rowA = row0 + g * 4 + r;
        xw[rowA * XW_STRIDE + col] = (f16)acc0[r];
        xw[(rowA + 16) * XW_STRIDE + col] = (f16)acc1[r];
      }
    }
  }
}

// ---------------- Phase 2: one wave64 per row; U in LDS ----------------------
// Lane l<50 owns h[l]. U lives in per-lane LDS rows (336B stride, b128
// conflict-free): no 75-reg loop-invariant U set for the allocator to park
// in AGPRs. h broadcast via uniform b128 reads. One wave's DS ops are
// in-order -> no fences; global xw prefetch ring stays in flight.
// NOTE: xzf/xrf/xhf are captured BEFORE the prefetch refill (round-14 bug:
// refill-first overwrote the slot and gates consumed t+4's xw).
__global__ __launch_bounds__(64, 1) void gru_head64(const f16* __restrict__ xw,
                                                    const float* __restrict__ U,
                                                    const float* __restrict__ bias,
                                                    const float* __restrict__ W2,
                                                    const float* __restrict__ b2,
                                                    float* __restrict__ out) {
  __shared__ __align__(16) f16 h_lds16[64];
  __shared__ __align__(16) f16 Ul[64 * UROW];  // [lane][uz:0..49|pad|ur:56..|pad|uh:112..]
  __shared__ float fin[52];
  __shared__ float red[8];
  const int l = threadIdx.x;
  const int b = blockIdx.x;
  const int lc = l < H ? l : H - 1;
  const bool act = l < H;
  const long base = (long)b * T_LEN * XW_STRIDE;

  f16* myU = Ul + l * UROW;
#pragma unroll
  for (int c = 0; c < 25; ++c) {
    *(f16x2*)(myU + 2 * c) =
        (f16x2){(f16)U[(2 * c) * H3 + lc], (f16)U[(2 * c + 1) * H3 + lc]};
    *(f16x2*)(myU + 56 + 2 * c) =
        (f16x2){(f16)U[(2 * c) * H3 + H + lc], (f16)U[(2 * c + 1) * H3 + H + lc]};
    *(f16x2*)(myU + 112 + 2 * c) =
        (f16x2){(f16)U[(2 * c) * H3 + 2 * H + lc],
                (f16)U[(2 * c + 1) * H3 + 2 * H + lc]};
  }
  const float bz = bias[lc] + bias[H3 + lc];
  const float br = bias[H + lc] + bias[H3 + H + lc];
  const float b0h = bias[2 * H + lc];
  const float b1h = bias[H3 + 2 * H + lc];

  float hreg = 0.f;
  h_lds16[l] = (f16)0.f;

  const f16* q = xw + base + lc;
  f16 pz[4], pr[4], ph[4];
#pragma unroll
  for (int p = 0; p < 4; ++p) {
    pz[p] = q[p * XW_STRIDE];
    pr[p] = q[p * XW_STRIDE + H];
    ph[p] = q[p * XW_STRIDE + 2 * H];
  }

  const f16x8* hp8 = (const f16x8*)h_lds16;
  const f16x8* uzp = (const f16x8*)(myU);
  const f16x8* urp = (const f16x8*)(myU + 56);
  const f16x8* uhp = (const f16x8*)(myU + 112);

#define EX4(DST, SRC, B)                                                      \
  DST[B] = __builtin_shufflevector(SRC, SRC, 0, 1);                           \
  DST[B + 1] = __builtin_shufflevector(SRC, SRC, 2, 3);                       \
  DST[B + 2] = __builtin_shufflevector(SRC, SRC, 4, 5);                       \
  DST[B + 3] = __builtin_shufflevector(SRC, SRC, 6, 7);

#define STEP(P, PF)                                                           \
    {                                                                         \
      /* capture current xw BEFORE refilling the ring slot (r14 bug) */       \
      float xzf = (float)pz[P];                                               \
      float xrf = (float)pr[P];                                               \
      float xhf = (float)ph[P];                                               \
      if (PF) {                                                               \
        pz[P] = q[(P + 4) * XW_STRIDE];                                       \
        pr[P] = q[(P + 4) * XW_STRIDE + H];                                   \
        ph[P] = q[(P + 4) * XW_STRIDE + 2 * H];                               \
      }                                                                       \
      f16x2 uzv[25], urv[25], uhv[25], hv[25];                                \
      _Pragma("unroll")                                                       \
      for (int i = 0; i < 6; ++i) { f16x8 t = uzp[i]; EX4(uzv, t, 4 * i) }    \
      uzv[24] = *(const f16x2*)(myU + 48);                                    \
      _Pragma("unroll")                                                       \
      for (int i = 0; i < 6; ++i) { f16x8 t = urp[i]; EX4(urv, t, 4 * i) }    \
      urv[24] = *(const f16x2*)(myU + 56 + 48);                               \
      _Pragma("unroll")                                                       \
      for (int i = 0; i < 6; ++i) { f16x8 t = uhp[i]; EX4(uhv, t, 4 * i) }    \
      uhv[24] = *(const f16x2*)(myU + 112 + 48);                              \
      {                                                                       \
        f16x8 w0 = hp8[0], w1 = hp8[1], w2 = hp8[2];                          \
        f16x8 w3 = hp8[3], w4 = hp8[4], w5 = hp8[5];                          \
        EX4(hv, w0, 0) EX4(hv, w1, 4) EX4(hv, w2, 8)                          \
        EX4(hv, w3, 12) EX4(hv, w4, 16) EX4(hv, w5, 20)                       \
        hv[24] = *(const f16x2*)(h_lds16 + 48);                               \
      }                                                                       \
      float sz0 = bz, sr0 = br, sh0 = b1h;                                    \
      float sz1 = 0.f, sr1 = 0.f, sh1 = 0.f;                                  \
      _Pragma("unroll")                                                       \
      for (int p = 0; p < 25; ++p) {                                          \
        if (p & 1) {                                                          \
          sz1 = dot2f(hv[p], uzv[p], sz1);                                    \
          sr1 = dot2f(hv[p], urv[p], sr1);                                    \
          sh1 = dot2f(hv[p], uhv[p], sh1);                                    \
        } else {                                                              \
          sz0 = dot2f(hv[p], uzv[p], sz0);                                    \
          sr0 = dot2f(hv[p], urv[p], sr0);                                    \
          sh0 = dot2f(hv[p], uhv[p], sh0);                                    \
        }                                                                     \
      }                                                                       \
      float ar = (sr0 + sr1) + xrf;                                           \
      float er = __expf(-ar);                                                 \
      float az = (sz0 + sz1) + xzf;                                           \
      float ez = __expf(-az);                                                 \
      float rr = rcpf(1.f + er);                                              \
      float zz = rcpf(1.f + ez);                                              \
      float ah = fmaf(rr, sh0 + sh1, xhf + b0h);                              \
      float eh = __expf(-2.f * ah);                                           \
      float th = fmaf(2.f, rcpf(1.f + eh), -1.f);                             \
      hreg = fmaf(zz, hreg - th, th);                                         \
      h_lds16[l] = (f16)hreg;                                                 \
    }

  for (int t0 = 0; t0 < T_LEN - 4; t0 += 4) {
    STEP(0, 1) STEP(1, 1) STEP(2, 1) STEP(3, 1)
    q += 4 * XW_STRIDE;
  }
  // final group: no prefetch (avoids OOB reads past the workspace)
  STEP(0, 0) STEP(1, 0) STEP(2, 0) STEP(3, 0)
#undef STEP
#undef EX4

  // LeakyReLU(0.3) + dense(50->8) + softmax, single wave, in-order LDS
  if (act) {
    fin[l] = hreg >= 0.f ? hreg : 0.3f * hreg;
  }
  if (l < 8) {
    float acc = b2[l];
#pragma unroll
    for (int j = 0; j < H; ++j) acc = fmaf(fin[j], W2[j * 8 + l], acc);
    red[l] = acc;
  }
  if (l < 8) {
    float m = red[0];
#pragma unroll
    for (int i = 1; i < 8; ++i) m = fmaxf(m, red[i]);
    float s = 0.f;
#pragma unroll
    for (int i = 0; i < 8; ++i) s += __expf(red[i] - m);
    out[b * 8 + l] = __expf(red[l] - m) / s;
  }
}

extern "C" void kernel_launch(void* const* d_in, const int* in_sizes, int n_in,
                              void* d_out, int out_size, void* d_ws, size_t ws_size,
                              hipStream_t stream) {
  const float* x = (const float*)d_in[0];
  const float* W = (const float*)d_in[1];
  const float* U = (const float*)d_in[2];
  const float* bias = (const float*)d_in[3];
  const float* W2 = (const float*)d_in[4];
  const float* b2 = (const float*)d_in[5];
  float* out = (float*)d_out;
  f16* xw = (f16*)d_ws;  // [B*T][160] f16, ~168 MB

  xw_gemm<<<4096, 256, 0, stream>>>(x, W, xw);
  gru_head64<<<256, 64, 0, stream>>>(xw, U, bias, W2, b2, out);
}